// Round 1
// baseline (277.927 us; speedup 1.0000x reference)
//
#include <hip/hip_runtime.h>
#include <math.h>

#define BS 32
#define NN 512
#define NDIMS 3
#define HNF 6
#define HID 64
#define EPSV 1e-8f
#define NORMC 1.0f

// ---------------------------------------------------------------------------
// Kernel 1: per-batch mean removal + tiny MLP (h -> silu(h@W1+b1)@W2+b2)
// One block per batch (32 blocks), one thread per node (512 threads).
// Writes centered x (BS*N*3) and h_emb (BS*N*2) into workspace.
// ---------------------------------------------------------------------------
__global__ __launch_bounds__(512) void prep_kernel(
    const float* __restrict__ xh,     // (BS, N, 9)
    const float* __restrict__ mask,   // (BS, N, 1)
    const float* __restrict__ W1,     // (6, 64)
    const float* __restrict__ b1,     // (64,)
    const float* __restrict__ W2,     // (64, 2)
    const float* __restrict__ b2,     // (2,)
    float* __restrict__ xc,           // (BS, N, 3) out
    float* __restrict__ hemb)         // (BS, N, 2) out
{
    const int b = blockIdx.x;
    const int i = threadIdx.x;

    __shared__ float s_red[8][4];
    __shared__ float s_mean[3];
    __shared__ float sW1[HNF * HID];
    __shared__ float sb1[HID];
    __shared__ float sW2[HID * 2];
    __shared__ float sb2[2];

    // stage weights
    for (int t = i; t < HNF * HID; t += 512) sW1[t] = W1[t];
    if (i < HID)     sb1[i] = b1[i];
    for (int t = i; t < HID * 2; t += 512) sW2[t] = W2[t];
    if (i < 2)       sb2[i] = b2[i];

    const float* row = xh + ((size_t)b * NN + i) * (NDIMS + HNF);
    float x0 = row[0], x1 = row[1], x2 = row[2];
    float h[HNF];
    #pragma unroll
    for (int k = 0; k < HNF; ++k) h[k] = row[NDIMS + k];
    float m = mask[(size_t)b * NN + i];

    // wave (64-lane) reduction of x sums and mask sum
    float v0 = x0, v1 = x1, v2 = x2, vm = m;
    #pragma unroll
    for (int off = 32; off > 0; off >>= 1) {
        v0 += __shfl_down(v0, off);
        v1 += __shfl_down(v1, off);
        v2 += __shfl_down(v2, off);
        vm += __shfl_down(vm, off);
    }
    const int lane = i & 63, wave = i >> 6;
    if (lane == 0) {
        s_red[wave][0] = v0; s_red[wave][1] = v1;
        s_red[wave][2] = v2; s_red[wave][3] = vm;
    }
    __syncthreads();
    if (i == 0) {
        float t0 = 0.f, t1 = 0.f, t2 = 0.f, tm = 0.f;
        #pragma unroll
        for (int w = 0; w < 8; ++w) {
            t0 += s_red[w][0]; t1 += s_red[w][1];
            t2 += s_red[w][2]; tm += s_red[w][3];
        }
        s_mean[0] = t0 / tm; s_mean[1] = t1 / tm; s_mean[2] = t2 / tm;
    }
    __syncthreads();

    // centered x
    float cx0 = x0 - s_mean[0] * m;
    float cx1 = x1 - s_mean[1] * m;
    float cx2 = x2 - s_mean[2] * m;
    float* xo = xc + ((size_t)b * NN + i) * 3;
    xo[0] = cx0; xo[1] = cx1; xo[2] = cx2;

    // tiny MLP: z = h@W1+b1 (64), a = silu(z), out = a@W2+b2 (2)
    float acc0 = sb2[0], acc1 = sb2[1];
    #pragma unroll 8
    for (int hh = 0; hh < HID; ++hh) {
        float z = sb1[hh];
        #pragma unroll
        for (int k = 0; k < HNF; ++k) z += h[k] * sW1[k * HID + hh];
        float s = z / (1.0f + expf(-z));   // silu
        acc0 += s * sW2[hh * 2 + 0];
        acc1 += s * sW2[hh * 2 + 1];
    }
    float* ho = hemb + ((size_t)b * NN + i) * 2;
    ho[0] = acc0; ho[1] = acc1;
}

// ---------------------------------------------------------------------------
// Kernel 2: edge features. Block per (b, i) row; thread per j.
// out[b,i,j,0:8] = [radial, cd0, cd1, cd2, hi0, hi1, hj0, hj1]
// ---------------------------------------------------------------------------
__global__ __launch_bounds__(512) void edge_kernel(
    const float* __restrict__ xc,     // (BS, N, 3)
    const float* __restrict__ hemb,   // (BS, N, 2)
    float4* __restrict__ out4)        // (BS*N*N*2) float4
{
    const int bi = blockIdx.x;            // b*N + i
    const int b  = bi >> 9;               // / 512
    const int i  = bi & (NN - 1);
    const int j  = threadIdx.x;

    __shared__ float sx[NN * 3];
    __shared__ float sh[NN * 2];

    const float* xb = xc   + (size_t)b * NN * 3;
    const float* hb = hemb + (size_t)b * NN * 2;

    // coalesced LDS staging of the whole batch row set
    sx[j]           = xb[j];
    sx[j + 512]     = xb[j + 512];
    sx[j + 1024]    = xb[j + 1024];
    sh[j]           = hb[j];
    sh[j + 512]     = hb[j + 512];
    __syncthreads();

    const float xi0 = sx[i * 3 + 0], xi1 = sx[i * 3 + 1], xi2 = sx[i * 3 + 2];
    const float hi0 = sh[i * 2 + 0], hi1 = sh[i * 2 + 1];

    const float xj0 = sx[j * 3 + 0], xj1 = sx[j * 3 + 1], xj2 = sx[j * 3 + 2];
    const float hj0 = sh[j * 2 + 0], hj1 = sh[j * 2 + 1];

    const float d0 = xi0 - xj0;
    const float d1 = xi1 - xj1;
    const float d2 = xi2 - xj2;
    const float radial = d0 * d0 + d1 * d1 + d2 * d2;
    const float norm = sqrtf(radial + EPSV);
    const float inv = 1.0f / (norm + NORMC);

    const size_t e = ((size_t)bi * NN + j) * 2;
    out4[e + 0] = make_float4(radial, d0 * inv, d1 * inv, d2 * inv);
    out4[e + 1] = make_float4(hi0, hi1, hj0, hj1);
}

extern "C" void kernel_launch(void* const* d_in, const int* in_sizes, int n_in,
                              void* d_out, int out_size, void* d_ws, size_t ws_size,
                              hipStream_t stream) {
    const float* xh   = (const float*)d_in[0];
    const float* mask = (const float*)d_in[1];
    const float* W1   = (const float*)d_in[2];
    const float* b1   = (const float*)d_in[3];
    const float* W2   = (const float*)d_in[4];
    const float* b2   = (const float*)d_in[5];

    float* xc   = (float*)d_ws;                 // BS*N*3 floats
    float* hemb = xc + (size_t)BS * NN * 3;     // BS*N*2 floats

    prep_kernel<<<BS, 512, 0, stream>>>(xh, mask, W1, b1, W2, b2, xc, hemb);
    edge_kernel<<<BS * NN, 512, 0, stream>>>(xc, hemb, (float4*)d_out);
}

// Round 2
// 276.778 us; speedup vs baseline: 1.0041x; 1.0041x over previous
//
#include <hip/hip_runtime.h>
#include <math.h>

#define BS 32
#define NN 512
#define NDIMS 3
#define HNF 6
#define HID 64
#define EPSV 1e-8f
#define NORMC 1.0f
#define ROWS 8   // i-rows per block in edge kernel

// ---------------------------------------------------------------------------
// Kernel 1: per-batch mean removal + tiny MLP (h -> silu(h@W1+b1)@W2+b2)
// One block per batch (32 blocks), one thread per node (512 threads).
// ---------------------------------------------------------------------------
__global__ __launch_bounds__(512) void prep_kernel(
    const float* __restrict__ xh,     // (BS, N, 9)
    const float* __restrict__ mask,   // (BS, N, 1)
    const float* __restrict__ W1,     // (6, 64)
    const float* __restrict__ b1,     // (64,)
    const float* __restrict__ W2,     // (64, 2)
    const float* __restrict__ b2,     // (2,)
    float* __restrict__ xc,           // (BS, N, 3) out
    float* __restrict__ hemb)         // (BS, N, 2) out
{
    const int b = blockIdx.x;
    const int i = threadIdx.x;

    __shared__ float s_red[8][4];
    __shared__ float s_mean[3];
    __shared__ float sW1[HNF * HID];
    __shared__ float sb1[HID];
    __shared__ float sW2[HID * 2];
    __shared__ float sb2[2];

    for (int t = i; t < HNF * HID; t += 512) sW1[t] = W1[t];
    if (i < HID) sb1[i] = b1[i];
    for (int t = i; t < HID * 2; t += 512) sW2[t] = W2[t];
    if (i < 2)   sb2[i] = b2[i];

    const float* row = xh + ((size_t)b * NN + i) * (NDIMS + HNF);
    float x0 = row[0], x1 = row[1], x2 = row[2];
    float h[HNF];
    #pragma unroll
    for (int k = 0; k < HNF; ++k) h[k] = row[NDIMS + k];
    float m = mask[(size_t)b * NN + i];

    float v0 = x0, v1 = x1, v2 = x2, vm = m;
    #pragma unroll
    for (int off = 32; off > 0; off >>= 1) {
        v0 += __shfl_down(v0, off);
        v1 += __shfl_down(v1, off);
        v2 += __shfl_down(v2, off);
        vm += __shfl_down(vm, off);
    }
    const int lane = i & 63, wave = i >> 6;
    if (lane == 0) {
        s_red[wave][0] = v0; s_red[wave][1] = v1;
        s_red[wave][2] = v2; s_red[wave][3] = vm;
    }
    __syncthreads();
    if (i == 0) {
        float t0 = 0.f, t1 = 0.f, t2 = 0.f, tm = 0.f;
        #pragma unroll
        for (int w = 0; w < 8; ++w) {
            t0 += s_red[w][0]; t1 += s_red[w][1];
            t2 += s_red[w][2]; tm += s_red[w][3];
        }
        s_mean[0] = t0 / tm; s_mean[1] = t1 / tm; s_mean[2] = t2 / tm;
    }
    __syncthreads();

    float cx0 = x0 - s_mean[0] * m;
    float cx1 = x1 - s_mean[1] * m;
    float cx2 = x2 - s_mean[2] * m;
    float* xo = xc + ((size_t)b * NN + i) * 3;
    xo[0] = cx0; xo[1] = cx1; xo[2] = cx2;

    float acc0 = sb2[0], acc1 = sb2[1];
    #pragma unroll 8
    for (int hh = 0; hh < HID; ++hh) {
        float z = sb1[hh];
        #pragma unroll
        for (int k = 0; k < HNF; ++k) z += h[k] * sW1[k * HID + hh];
        float s = z / (1.0f + expf(-z));   // silu
        acc0 += s * sW2[hh * 2 + 0];
        acc1 += s * sW2[hh * 2 + 1];
    }
    float* ho = hemb + ((size_t)b * NN + i) * 2;
    ho[0] = acc0; ho[1] = acc1;
}

// ---------------------------------------------------------------------------
// Kernel 2: edge features, ROWS i-rows per block, fully coalesced stores.
// Output row (b,i) = 1024 float4. Thread j writes slots j and j+512:
//   slot q -> edge q>>1, half q&1 (half0 = radial+coord_diff, half1 = h_i,h_j)
// ---------------------------------------------------------------------------
__global__ __launch_bounds__(512) void edge_kernel(
    const float* __restrict__ xc,     // (BS, N, 3)
    const float* __restrict__ hemb,   // (BS, N, 2)
    float4* __restrict__ out4)        // BS*N*N*2 float4
{
    const int blk = blockIdx.x;           // 0 .. BS*NN/ROWS-1
    const int bi0 = blk * ROWS;
    const int b   = bi0 >> 9;
    const int i0  = bi0 & (NN - 1);
    const int j   = threadIdx.x;

    __shared__ float sx[NN * 3];
    __shared__ float sh[NN * 2];

    const float* xb = xc   + (size_t)b * NN * 3;
    const float* hb = hemb + (size_t)b * NN * 2;
    sx[j]        = xb[j];
    sx[j + 512]  = xb[j + 512];
    sx[j + 1024] = xb[j + 1024];
    sh[j]        = hb[j];
    sh[j + 512]  = hb[j + 512];
    __syncthreads();

    const int ja = j >> 1;            // edge for slot j
    const int jb = 256 + ja;          // edge for slot j+512
    const bool odd = (j & 1) != 0;    // half selector

    const float xa0 = sx[ja * 3 + 0], xa1 = sx[ja * 3 + 1], xa2 = sx[ja * 3 + 2];
    const float xb0 = sx[jb * 3 + 0], xb1 = sx[jb * 3 + 1], xb2 = sx[jb * 3 + 2];
    const float ha0 = sh[ja * 2 + 0], ha1 = sh[ja * 2 + 1];
    const float hb0 = sh[jb * 2 + 0], hb1 = sh[jb * 2 + 1];

    float4* rowout = out4 + (size_t)bi0 * NN * 2;

    #pragma unroll
    for (int r = 0; r < ROWS; ++r) {
        const int i = i0 + r;
        const float xi0 = sx[i * 3 + 0], xi1 = sx[i * 3 + 1], xi2 = sx[i * 3 + 2];
        const float hi0 = sh[i * 2 + 0], hi1 = sh[i * 2 + 1];

        float d0 = xi0 - xa0, d1 = xi1 - xa1, d2 = xi2 - xa2;
        float rada = d0 * d0 + d1 * d1 + d2 * d2;
        float inva = __builtin_amdgcn_rcpf(__builtin_amdgcn_sqrtf(rada + EPSV) + NORMC);
        float4 va = odd ? make_float4(hi0, hi1, ha0, ha1)
                        : make_float4(rada, d0 * inva, d1 * inva, d2 * inva);

        float e0 = xi0 - xb0, e1 = xi1 - xb1, e2 = xi2 - xb2;
        float radb = e0 * e0 + e1 * e1 + e2 * e2;
        float invb = __builtin_amdgcn_rcpf(__builtin_amdgcn_sqrtf(radb + EPSV) + NORMC);
        float4 vb = odd ? make_float4(hi0, hi1, hb0, hb1)
                        : make_float4(radb, e0 * invb, e1 * invb, e2 * invb);

        rowout[j]       = va;   // contiguous 1KB wave store
        rowout[j + 512] = vb;   // contiguous 1KB wave store
        rowout += NN * 2;
    }
}

extern "C" void kernel_launch(void* const* d_in, const int* in_sizes, int n_in,
                              void* d_out, int out_size, void* d_ws, size_t ws_size,
                              hipStream_t stream) {
    const float* xh   = (const float*)d_in[0];
    const float* mask = (const float*)d_in[1];
    const float* W1   = (const float*)d_in[2];
    const float* b1   = (const float*)d_in[3];
    const float* W2   = (const float*)d_in[4];
    const float* b2   = (const float*)d_in[5];

    float* xc   = (float*)d_ws;                 // BS*N*3 floats
    float* hemb = xc + (size_t)BS * NN * 3;     // BS*N*2 floats

    prep_kernel<<<BS, 512, 0, stream>>>(xh, mask, W1, b1, W2, b2, xc, hemb);
    edge_kernel<<<BS * NN / ROWS, 512, 0, stream>>>(xc, hemb, (float4*)d_out);
}